// Round 6
// baseline (175.189 us; speedup 1.0000x reference)
//
#include <hip/hip_runtime.h>
#include <math.h>

// B=16, C=64, H=W=112, WS=7 -> 784 tiles of 16x16 pixels
#define CC    64
#define CF    16
#define NPIX  256
#define KK    9
#define HWQ   12544
#define WWQ   112
#define NTILE 784
#define NROWS (NTILE * NPIX)   // 200704
#define MBLK  128              // r5 fallback kernel block size

// ============================================================
// Kernel 1: per-pixel features f = Wf@x + bf, normalize.
// ============================================================
__global__ __launch_bounds__(64, 4) void feat_k(
    const float* __restrict__ x_in, const float* __restrict__ Wf,
    const float* __restrict__ bf,
    float* __restrict__ xn_g, float* __restrict__ nrm_g)
{
    __shared__ float s_Wt[CC * CF];   // transposed [c][o]
    __shared__ float s_bf[CF];
    const int tid = threadIdx.x;
    for (int idx = tid; idx < CC * CF; idx += 64) {
        int c = idx >> 4, o = idx & 15;
        s_Wt[idx] = Wf[o * CC + c];
    }
    if (tid < CF) s_bf[tid] = bf[tid];
    __syncthreads();

    const int p    = blockIdx.x * 64 + tid;
    const int tile = p >> 8, pix = p & 255;
    const int bb = tile / 49, ssb = tile % 49;
    const int s1 = ssb / 7, s2 = ssb % 7;
    const int gy = s1 * 16 + (pix >> 4), gx = s2 * 16 + (pix & 15);
    const float* xb = x_in + (size_t)bb * CC * HWQ + (size_t)gy * WWQ + gx;

    float fv[CF];
    #pragma unroll
    for (int o = 0; o < CF; ++o) fv[o] = 0.0f;
    #pragma unroll 8
    for (int c = 0; c < CC; ++c) {
        float xv = xb[(size_t)c * HWQ];
        const float4* w4 = reinterpret_cast<const float4*>(&s_Wt[c << 4]);
        float4 w0 = w4[0], w1 = w4[1], w2 = w4[2], w3 = w4[3];
        fv[0]  = fmaf(xv, w0.x, fv[0]);  fv[1]  = fmaf(xv, w0.y, fv[1]);
        fv[2]  = fmaf(xv, w0.z, fv[2]);  fv[3]  = fmaf(xv, w0.w, fv[3]);
        fv[4]  = fmaf(xv, w1.x, fv[4]);  fv[5]  = fmaf(xv, w1.y, fv[5]);
        fv[6]  = fmaf(xv, w1.z, fv[6]);  fv[7]  = fmaf(xv, w1.w, fv[7]);
        fv[8]  = fmaf(xv, w2.x, fv[8]);  fv[9]  = fmaf(xv, w2.y, fv[9]);
        fv[10] = fmaf(xv, w2.z, fv[10]); fv[11] = fmaf(xv, w2.w, fv[11]);
        fv[12] = fmaf(xv, w3.x, fv[12]); fv[13] = fmaf(xv, w3.y, fv[13]);
        fv[14] = fmaf(xv, w3.z, fv[14]); fv[15] = fmaf(xv, w3.w, fv[15]);
    }
    #pragma unroll
    for (int o = 0; o < CF; ++o) fv[o] += s_bf[o];

    float ss2 = 0.0f;
    #pragma unroll
    for (int o = 0; o < CF; ++o) ss2 = fmaf(fv[o], fv[o], ss2);
    float nrm = fmaxf(sqrtf(ss2), 1e-8f);

    float xn[CF];
    #pragma unroll
    for (int o = 0; o < CF; ++o) xn[o] = fv[o] / nrm;

    float4* dst = reinterpret_cast<float4*>(xn_g + (size_t)p * CF);
    dst[0] = make_float4(xn[0],  xn[1],  xn[2],  xn[3]);
    dst[1] = make_float4(xn[4],  xn[5],  xn[6],  xn[7]);
    dst[2] = make_float4(xn[8],  xn[9],  xn[10], xn[11]);
    dst[3] = make_float4(xn[12], xn[13], xn[14], xn[15]);
    nrm_g[p] = nrm;
}

// ---------------- shared scan machinery ----------------
#define DOT16(dot, a0, a1, a2, a3)                                   \
    dot = fmaf(xnr[0],  (a0).x, dot); dot = fmaf(xnr[1],  (a0).y, dot); \
    dot = fmaf(xnr[2],  (a0).z, dot); dot = fmaf(xnr[3],  (a0).w, dot); \
    dot = fmaf(xnr[4],  (a1).x, dot); dot = fmaf(xnr[5],  (a1).y, dot); \
    dot = fmaf(xnr[6],  (a1).z, dot); dot = fmaf(xnr[7],  (a1).w, dot); \
    dot = fmaf(xnr[8],  (a2).x, dot); dot = fmaf(xnr[9],  (a2).y, dot); \
    dot = fmaf(xnr[10], (a2).z, dot); dot = fmaf(xnr[11], (a2).w, dot); \
    dot = fmaf(xnr[12], (a3).x, dot); dot = fmaf(xnr[13], (a3).y, dot); \
    dot = fmaf(xnr[14], (a3).z, dot); dot = fmaf(xnr[15], (a3).w, dot);

// guard-free sorted top-9 insert; strict '>' keeps lower index on ties,
// matching lax.top_k. Values via max/med3, indices via monotone cndmasks.
#define TOP9_INSERT(cv, ci) {                                        \
    const bool g0 = (cv) > tv0; const bool g1 = (cv) > tv1;          \
    const bool g2 = (cv) > tv2; const bool g3 = (cv) > tv3;          \
    const bool g4 = (cv) > tv4; const bool g5 = (cv) > tv5;          \
    const bool g6 = (cv) > tv6; const bool g7 = (cv) > tv7;          \
    const bool g8 = (cv) > tv8;                                      \
    const float nv0 = g0 ? (cv) : tv0;                               \
    const float nv1 = __builtin_amdgcn_fmed3f((cv), tv0, tv1);       \
    const float nv2 = __builtin_amdgcn_fmed3f((cv), tv1, tv2);       \
    const float nv3 = __builtin_amdgcn_fmed3f((cv), tv2, tv3);       \
    const float nv4 = __builtin_amdgcn_fmed3f((cv), tv3, tv4);       \
    const float nv5 = __builtin_amdgcn_fmed3f((cv), tv4, tv5);       \
    const float nv6 = __builtin_amdgcn_fmed3f((cv), tv5, tv6);       \
    const float nv7 = __builtin_amdgcn_fmed3f((cv), tv6, tv7);       \
    const float nv8 = __builtin_amdgcn_fmed3f((cv), tv7, tv8);       \
    const int nt0 = g0 ? (ci) : ti0;                                 \
    const int nt1 = g0 ? ti0 : (g1 ? (ci) : ti1);                    \
    const int nt2 = g1 ? ti1 : (g2 ? (ci) : ti2);                    \
    const int nt3 = g2 ? ti2 : (g3 ? (ci) : ti3);                    \
    const int nt4 = g3 ? ti3 : (g4 ? (ci) : ti4);                    \
    const int nt5 = g4 ? ti4 : (g5 ? (ci) : ti5);                    \
    const int nt6 = g5 ? ti5 : (g6 ? (ci) : ti6);                    \
    const int nt7 = g6 ? ti6 : (g7 ? (ci) : ti7);                    \
    const int nt8 = g7 ? ti7 : (g8 ? (ci) : ti8);                    \
    tv0 = nv0; tv1 = nv1; tv2 = nv2; tv3 = nv3; tv4 = nv4;           \
    tv5 = nv5; tv6 = nv6; tv7 = nv7; tv8 = nv8;                      \
    ti0 = nt0; ti1 = nt1; ti2 = nt2; ti3 = nt3; ti4 = nt4;           \
    ti5 = nt5; ti6 = nt6; ti7 = nt7; ti8 = nt8; }

#define SIM_ITER(MJ) {                                               \
    const int m = mbase + (MJ);                                      \
    const float4* xm4 = reinterpret_cast<const float4*>(&s_xn[m][0]);\
    const float4 a0 = xm4[0], a1 = xm4[1], a2 = xm4[2], a3 = xm4[3]; \
    float dot = 0.0f;                                                \
    DOT16(dot, a0, a1, a2, a3);                                      \
    const int dj = pj - (MJ);                                        \
    const float sdA = s_tabA[d2i + dj * dj];                         \
    const float comb = __fadd_rn(__fmul_rn(alpha, dot), sdA);        \
    TOP9_INSERT(comb, m); }

#define SIM_ROW16()                                                  \
        SIM_ITER(0)  SIM_ITER(1)  SIM_ITER(2)  SIM_ITER(3)           \
        SIM_ITER(4)  SIM_ITER(5)  SIM_ITER(6)  SIM_ITER(7)           \
        SIM_ITER(8)  SIM_ITER(9)  SIM_ITER(10) SIM_ITER(11)          \
        SIM_ITER(12) SIM_ITER(13) SIM_ITER(14) SIM_ITER(15)

// ============================================================
// Kernel 2 (new): candidate-split scan. Block = 256 threads:
// 128 rows x 2 candidate halves; 4 waves share one staged tile.
// Hi-half waves write sorted partial top-9 to d_ws; lo-half waves
// merge via the same TOP9_INSERT (exact tie semantics) + epilogue.
// ============================================================
__global__ __launch_bounds__(256, 7) void gnn_split(
    const float* __restrict__ xn_g, const float* __restrict__ nrm_g,
    const float* __restrict__ Wp,   const float* __restrict__ bp,
    const float* __restrict__ W1,   const float* __restrict__ b1,
    const float* __restrict__ W2,   const float* __restrict__ b2,
    const float* __restrict__ sigma_p, const float* __restrict__ alpha_p,
    float* __restrict__ pval, int* __restrict__ pidx,
    float* __restrict__ y)
{
    __shared__ float s_xn[NPIX][CF];   // 16 KB tile features
    __shared__ float s_nrm[NPIX];      // 1 KB
    __shared__ float s_tab[451];       // raw exp(-d^2/(2 sigma^2))
    __shared__ float s_tabA[451];      // (1-alpha) * table

    const int bid  = blockIdx.x;
    const int tile = bid >> 1;
    const int hlf  = bid & 1;          // row half of the tile
    const int bb = tile / 49, ssb = tile % 49;
    const int s1 = ssb / 7, s2 = ssb % 7;
    const int tid = threadIdx.x;
    const int rl  = tid & 127;         // row within half
    const int ch  = tid >> 7;          // candidate half (0 = lo, 1 = hi)

    const float alpha = alpha_p[0];
    const float oma   = 1.0f - alpha;
    const float sig   = sigma_p[0];
    const float denom = 2.0f * sig * sig;

    for (int t = tid; t < 451; t += 256) {
        float dd = sqrtf((float)t);
        float v  = expf((-(dd * dd)) / denom);
        s_tab[t]  = v;
        s_tabA[t] = __fmul_rn(oma, v);
    }
    const float* xt = xn_g + (size_t)tile * NPIX * CF;
    {
        const float4* src = reinterpret_cast<const float4*>(xt);
        float4*       dst = reinterpret_cast<float4*>(&s_xn[0][0]);
        #pragma unroll
        for (int i = 0; i < 4; ++i) dst[tid + i * 256] = src[tid + i * 256];
        s_nrm[tid] = nrm_g[(size_t)tile * NPIX + tid];
    }
    float W1r[8], b1r[4], W2r[4];
    #pragma unroll
    for (int h = 0; h < 8; ++h) W1r[h] = W1[h];
    #pragma unroll
    for (int h = 0; h < 4; ++h) { b1r[h] = b1[h]; W2r[h] = W2[h]; }
    const float b2r = b2[0];
    __syncthreads();

    const int r  = hlf * 128 + rl;     // this thread's row 0..255
    const int pi = r >> 4, pj = r & 15;
    const int gRow = tile * NPIX + r;

    float xnr[CF];
    {
        const float4* xr4 = reinterpret_cast<const float4*>(&s_xn[r][0]);
        float4 r0 = xr4[0], r1 = xr4[1], r2 = xr4[2], r3 = xr4[3];
        xnr[0]=r0.x;  xnr[1]=r0.y;  xnr[2]=r0.z;  xnr[3]=r0.w;
        xnr[4]=r1.x;  xnr[5]=r1.y;  xnr[6]=r1.z;  xnr[7]=r1.w;
        xnr[8]=r2.x;  xnr[9]=r2.y;  xnr[10]=r2.z; xnr[11]=r2.w;
        xnr[12]=r3.x; xnr[13]=r3.y; xnr[14]=r3.z; xnr[15]=r3.w;
    }

    float tv0,tv1,tv2,tv3,tv4,tv5,tv6,tv7,tv8;
    int   ti0,ti1,ti2,ti3,ti4,ti5,ti6,ti7,ti8;
    tv0=tv1=tv2=tv3=tv4=tv5=tv6=tv7=tv8 = -INFINITY;
    ti0=ti1=ti2=ti3=ti4=ti5=ti6=ti7=ti8 = 0;

    // scan this thread's candidate half: mi in [ch*8, ch*8+8)
    const int mi0 = ch << 3;
    #pragma unroll 1
    for (int q = 0; q < 8; ++q) {
        const int mi  = mi0 + q;
        const int di  = pi - mi;
        const int d2i = di * di;
        const int mbase = mi << 4;
        SIM_ROW16()
    }

    // hi-half waves publish their sorted partials (k-major = coalesced)
    if (ch == 1) {
        pval[0 * NROWS + gRow] = tv0; pidx[0 * NROWS + gRow] = ti0;
        pval[1 * NROWS + gRow] = tv1; pidx[1 * NROWS + gRow] = ti1;
        pval[2 * NROWS + gRow] = tv2; pidx[2 * NROWS + gRow] = ti2;
        pval[3 * NROWS + gRow] = tv3; pidx[3 * NROWS + gRow] = ti3;
        pval[4 * NROWS + gRow] = tv4; pidx[4 * NROWS + gRow] = ti4;
        pval[5 * NROWS + gRow] = tv5; pidx[5 * NROWS + gRow] = ti5;
        pval[6 * NROWS + gRow] = tv6; pidx[6 * NROWS + gRow] = ti6;
        pval[7 * NROWS + gRow] = tv7; pidx[7 * NROWS + gRow] = ti7;
        pval[8 * NROWS + gRow] = tv8; pidx[8 * NROWS + gRow] = ti8;
    }
    __syncthreads();
    if (ch == 1) return;

    // lo-half waves merge hi partials: sorted-desc b0..b8 inserted in order
    // through the identical strict-'>' insert => exact 256-wide semantics
    // (all lo indices < hi indices, ties keep lo; hi internal order kept).
    #pragma unroll
    for (int k = 0; k < KK; ++k) {
        const float bv = pval[k * NROWS + gRow];
        const int   bi = pidx[k * NROWS + gRow];
        TOP9_INSERT(bv, bi);
    }

    const float tv[KK] = {tv0,tv1,tv2,tv3,tv4,tv5,tv6,tv7,tv8};
    const int   ti[KK] = {ti0,ti1,ti2,ti3,ti4,ti5,ti6,ti7,ti8};

    // ---- edge MLP weights ----
    float wk[KK];
    float wsum = 0.0f;
    #pragma unroll
    for (int k = 0; k < KK; ++k) {
        int m = ti[k];
        int di = pi - (m >> 4);
        int dj = pj - (m & 15);
        float sd = s_tab[di * di + dj * dj];
        float sf = (tv[k] - __fmul_rn(oma, sd)) / alpha;
        float hsum = b2r;
        #pragma unroll
        for (int h = 0; h < 4; ++h) {
            float z  = fmaf(sf, W1r[2 * h], fmaf(sd, W1r[2 * h + 1], b1r[h]));
            float sg = 1.0f / (1.0f + expf(-z));
            hsum = fmaf(z * sg, W2r[h], hsum);
        }
        float wg = 1.0f / (1.0f + expf(-hsum));
        wk[k] = wg;
        wsum += wg;
    }
    wsum += 1e-12f;

    // ---- aggregate messages (msg = xn * nrm) ----
    float outv[CF];
    #pragma unroll
    for (int o = 0; o < CF; ++o) outv[o] = 0.0f;
    #pragma unroll
    for (int k = 0; k < KK; ++k) {
        const int m = ti[k];
        const float wnm = (wk[k] / wsum) * s_nrm[m];
        const float4* xf4 = reinterpret_cast<const float4*>(&s_xn[m][0]);
        float4 m0 = xf4[0], m1 = xf4[1], m2 = xf4[2], m3 = xf4[3];
        outv[0]  = fmaf(wnm, m0.x, outv[0]);  outv[1]  = fmaf(wnm, m0.y, outv[1]);
        outv[2]  = fmaf(wnm, m0.z, outv[2]);  outv[3]  = fmaf(wnm, m0.w, outv[3]);
        outv[4]  = fmaf(wnm, m1.x, outv[4]);  outv[5]  = fmaf(wnm, m1.y, outv[5]);
        outv[6]  = fmaf(wnm, m1.z, outv[6]);  outv[7]  = fmaf(wnm, m1.w, outv[7]);
        outv[8]  = fmaf(wnm, m2.x, outv[8]);  outv[9]  = fmaf(wnm, m2.y, outv[9]);
        outv[10] = fmaf(wnm, m2.z, outv[10]); outv[11] = fmaf(wnm, m2.w, outv[11]);
        outv[12] = fmaf(wnm, m3.x, outv[12]); outv[13] = fmaf(wnm, m3.y, outv[13]);
        outv[14] = fmaf(wnm, m3.z, outv[14]); outv[15] = fmaf(wnm, m3.w, outv[15]);
    }

    // ---- project 16 -> 64, store (Wp/bp uniform from L1/L2) ----
    const int gy = s1 * 16 + pi, gx = s2 * 16 + pj;
    float* yb = y + (size_t)bb * CC * HWQ + (size_t)gy * WWQ + gx;
    #pragma unroll 4
    for (int o = 0; o < CC; ++o) {
        const float4* w4 = reinterpret_cast<const float4*>(&Wp[o * CF]);
        float4 w0 = w4[0], w1 = w4[1], w2 = w4[2], w3 = w4[3];
        float acc = 0.0f;
        acc = fmaf(outv[0],  w0.x, acc); acc = fmaf(outv[1],  w0.y, acc);
        acc = fmaf(outv[2],  w0.z, acc); acc = fmaf(outv[3],  w0.w, acc);
        acc = fmaf(outv[4],  w1.x, acc); acc = fmaf(outv[5],  w1.y, acc);
        acc = fmaf(outv[6],  w1.z, acc); acc = fmaf(outv[7],  w1.w, acc);
        acc = fmaf(outv[8],  w2.x, acc); acc = fmaf(outv[9],  w2.y, acc);
        acc = fmaf(outv[10], w2.z, acc); acc = fmaf(outv[11], w2.w, acc);
        acc = fmaf(outv[12], w3.x, acc); acc = fmaf(outv[13], w3.y, acc);
        acc = fmaf(outv[14], w3.z, acc); acc = fmaf(outv[15], w3.w, acc);
        yb[(size_t)o * HWQ] = acc + bp[o];
    }
}

// ============================================================
// Fallback A (r5, known-passing): 128-thread full-candidate scan.
// ============================================================
__global__ __launch_bounds__(MBLK, 4) void gnn_main_r5(
    const float* __restrict__ xn_g, const float* __restrict__ nrm_g,
    const float* __restrict__ Wp,   const float* __restrict__ bp,
    const float* __restrict__ W1,   const float* __restrict__ b1,
    const float* __restrict__ W2,   const float* __restrict__ b2,
    const float* __restrict__ sigma_p, const float* __restrict__ alpha_p,
    float* __restrict__ y)
{
    __shared__ float s_xn[NPIX][CF];
    __shared__ float s_nrm[NPIX];
    __shared__ float s_tab[451];
    __shared__ float s_tabA[451];

    const int bid  = blockIdx.x;
    const int tile = bid >> 1;
    const int hlf  = bid & 1;
    const int bb = tile / 49, ssb = tile % 49;
    const int s1 = ssb / 7, s2 = ssb % 7;
    const int tid = threadIdx.x;

    const float alpha = alpha_p[0];
    const float oma   = 1.0f - alpha;
    const float sig   = sigma_p[0];
    const float denom = 2.0f * sig * sig;

    for (int t = tid; t < 451; t += MBLK) {
        float dd = sqrtf((float)t);
        float v  = expf((-(dd * dd)) / denom);
        s_tab[t]  = v;
        s_tabA[t] = __fmul_rn(oma, v);
    }
    const float* xt = xn_g + (size_t)tile * NPIX * CF;
    {
        const float4* src = reinterpret_cast<const float4*>(xt);
        float4*       dst = reinterpret_cast<float4*>(&s_xn[0][0]);
        #pragma unroll
        for (int i = 0; i < 8; ++i) dst[tid + i * MBLK] = src[tid + i * MBLK];
        const float* nsrc = nrm_g + (size_t)tile * NPIX;
        s_nrm[tid]        = nsrc[tid];
        s_nrm[tid + MBLK] = nsrc[tid + MBLK];
    }
    float W1r[8], b1r[4], W2r[4];
    #pragma unroll
    for (int h = 0; h < 8; ++h) W1r[h] = W1[h];
    #pragma unroll
    for (int h = 0; h < 4; ++h) { b1r[h] = b1[h]; W2r[h] = W2[h]; }
    const float b2r = b2[0];
    __syncthreads();

    const int r  = hlf * MBLK + tid;
    const int pi = r >> 4, pj = r & 15;

    float xnr[CF];
    {
        const float4* xr4 = reinterpret_cast<const float4*>(&s_xn[r][0]);
        float4 r0 = xr4[0], r1 = xr4[1], r2 = xr4[2], r3 = xr4[3];
        xnr[0]=r0.x;  xnr[1]=r0.y;  xnr[2]=r0.z;  xnr[3]=r0.w;
        xnr[4]=r1.x;  xnr[5]=r1.y;  xnr[6]=r1.z;  xnr[7]=r1.w;
        xnr[8]=r2.x;  xnr[9]=r2.y;  xnr[10]=r2.z; xnr[11]=r2.w;
        xnr[12]=r3.x; xnr[13]=r3.y; xnr[14]=r3.z; xnr[15]=r3.w;
    }

    float tv0,tv1,tv2,tv3,tv4,tv5,tv6,tv7,tv8;
    int   ti0,ti1,ti2,ti3,ti4,ti5,ti6,ti7,ti8;
    tv0=tv1=tv2=tv3=tv4=tv5=tv6=tv7=tv8 = -INFINITY;
    ti0=ti1=ti2=ti3=ti4=ti5=ti6=ti7=ti8 = 0;

    #pragma unroll 1
    for (int mi = 0; mi < 16; ++mi) {
        const int di  = pi - mi;
        const int d2i = di * di;
        const int mbase = mi << 4;
        SIM_ROW16()
    }

    const float tv[KK] = {tv0,tv1,tv2,tv3,tv4,tv5,tv6,tv7,tv8};
    const int   ti[KK] = {ti0,ti1,ti2,ti3,ti4,ti5,ti6,ti7,ti8};

    float wk[KK];
    float wsum = 0.0f;
    #pragma unroll
    for (int k = 0; k < KK; ++k) {
        int m = ti[k];
        int di = pi - (m >> 4);
        int dj = pj - (m & 15);
        float sd = s_tab[di * di + dj * dj];
        float sf = (tv[k] - __fmul_rn(oma, sd)) / alpha;
        float hsum = b2r;
        #pragma unroll
        for (int h = 0; h < 4; ++h) {
            float z  = fmaf(sf, W1r[2 * h], fmaf(sd, W1r[2 * h + 1], b1r[h]));
            float sg = 1.0f / (1.0f + expf(-z));
            hsum = fmaf(z * sg, W2r[h], hsum);
        }
        float wg = 1.0f / (1.0f + expf(-hsum));
        wk[k] = wg;
        wsum += wg;
    }
    wsum += 1e-12f;

    float outv[CF];
    #pragma unroll
    for (int o = 0; o < CF; ++o) outv[o] = 0.0f;
    #pragma unroll
    for (int k = 0; k < KK; ++k) {
        const int m = ti[k];
        const float wnm = (wk[k] / wsum) * s_nrm[m];
        const float4* xf4 = reinterpret_cast<const float4*>(&s_xn[m][0]);
        float4 m0 = xf4[0], m1 = xf4[1], m2 = xf4[2], m3 = xf4[3];
        outv[0]  = fmaf(wnm, m0.x, outv[0]);  outv[1]  = fmaf(wnm, m0.y, outv[1]);
        outv[2]  = fmaf(wnm, m0.z, outv[2]);  outv[3]  = fmaf(wnm, m0.w, outv[3]);
        outv[4]  = fmaf(wnm, m1.x, outv[4]);  outv[5]  = fmaf(wnm, m1.y, outv[5]);
        outv[6]  = fmaf(wnm, m1.z, outv[6]);  outv[7]  = fmaf(wnm, m1.w, outv[7]);
        outv[8]  = fmaf(wnm, m2.x, outv[8]);  outv[9]  = fmaf(wnm, m2.y, outv[9]);
        outv[10] = fmaf(wnm, m2.z, outv[10]); outv[11] = fmaf(wnm, m2.w, outv[11]);
        outv[12] = fmaf(wnm, m3.x, outv[12]); outv[13] = fmaf(wnm, m3.y, outv[13]);
        outv[14] = fmaf(wnm, m3.z, outv[14]); outv[15] = fmaf(wnm, m3.w, outv[15]);
    }

    const int gy = s1 * 16 + pi, gx = s2 * 16 + pj;
    float* yb = y + (size_t)bb * CC * HWQ + (size_t)gy * WWQ + gx;
    #pragma unroll 4
    for (int o = 0; o < CC; ++o) {
        const float4* w4 = reinterpret_cast<const float4*>(&Wp[o * CF]);
        float4 w0 = w4[0], w1 = w4[1], w2 = w4[2], w3 = w4[3];
        float acc = 0.0f;
        acc = fmaf(outv[0],  w0.x, acc); acc = fmaf(outv[1],  w0.y, acc);
        acc = fmaf(outv[2],  w0.z, acc); acc = fmaf(outv[3],  w0.w, acc);
        acc = fmaf(outv[4],  w1.x, acc); acc = fmaf(outv[5],  w1.y, acc);
        acc = fmaf(outv[6],  w1.z, acc); acc = fmaf(outv[7],  w1.w, acc);
        acc = fmaf(outv[8],  w2.x, acc); acc = fmaf(outv[9],  w2.y, acc);
        acc = fmaf(outv[10], w2.z, acc); acc = fmaf(outv[11], w2.w, acc);
        acc = fmaf(outv[12], w3.x, acc); acc = fmaf(outv[13], w3.y, acc);
        acc = fmaf(outv[14], w3.z, acc); acc = fmaf(outv[15], w3.w, acc);
        yb[(size_t)o * HWQ] = acc + bp[o];
    }
}

// ============================================================
// Fallback B: round-1 fused kernel (no workspace needed).
// ============================================================
__global__ __launch_bounds__(256) void gnn_fused(
    const float* __restrict__ x_in, const float* __restrict__ Wf,
    const float* __restrict__ bf,   const float* __restrict__ Wp,
    const float* __restrict__ bp,   const float* __restrict__ W1,
    const float* __restrict__ b1,   const float* __restrict__ W2,
    const float* __restrict__ b2,   const float* __restrict__ sigma_p,
    const float* __restrict__ alpha_p, float* __restrict__ y)
{
    __shared__ float s_xf[NPIX][CF];
    __shared__ float s_xn[NPIX][CF];
    __shared__ float s_W[CC * CF];
    __shared__ float s_table[451];
    __shared__ float s_bias[CC];

    const int bpi = blockIdx.x;
    const int bb  = bpi / 49;
    const int ssb = bpi % 49;
    const int s1  = ssb / 7, s2 = ssb % 7;
    const int tid = threadIdx.x;
    const int pi  = tid >> 4, pj = tid & 15;
    const int gy  = s1 * 16 + pi, gx = s2 * 16 + pj;

    const float alpha = alpha_p[0];
    const float oma   = 1.0f - alpha;
    const float sig   = sigma_p[0];
    const float denom = 2.0f * sig * sig;

    for (int t = tid; t < CF * CC; t += NPIX) s_W[t] = Wf[t];
    if (tid < CF) s_bias[tid] = bf[tid];
    for (int t = tid; t < 451; t += NPIX) {
        float dd = sqrtf((float)t);
        s_table[t] = expf((-(dd * dd)) / denom);
    }
    float W1r[8], b1r[4], W2r[4];
    #pragma unroll
    for (int h = 0; h < 8; ++h) W1r[h] = W1[h];
    #pragma unroll
    for (int h = 0; h < 4; ++h) { b1r[h] = b1[h]; W2r[h] = W2[h]; }
    const float b2r = b2[0];
    __syncthreads();

    const float* xb = x_in + (size_t)bb * CC * HWQ + (size_t)gy * WWQ + gx;
    float fv[CF];
    #pragma unroll
    for (int o = 0; o < CF; ++o) fv[o] = 0.0f;
    for (int c = 0; c < CC; ++c) {
        float xv = xb[(size_t)c * HWQ];
        #pragma unroll
        for (int o = 0; o < CF; ++o)
            fv[o] = fmaf(xv, s_W[o * CC + c], fv[o]);
    }
    #pragma unroll
    for (int o = 0; o < CF; ++o) fv[o] += s_bias[o];

    float ss2 = 0.0f;
    #pragma unroll
    for (int o = 0; o < CF; ++o) ss2 = fmaf(fv[o], fv[o], ss2);
    float nrm = fmaxf(sqrtf(ss2), 1e-8f);

    float xnr[CF];
    #pragma unroll
    for (int o = 0; o < CF; ++o) {
        xnr[o] = fv[o] / nrm;
        s_xf[tid][o] = fv[o];
        s_xn[tid][o] = xnr[o];
    }
    __syncthreads();

    float tv[KK]; int ti[KK];
    #pragma unroll
    for (int k = 0; k < KK; ++k) { tv[k] = -INFINITY; ti[k] = 0; }

    for (int m = 0; m < NPIX; ++m) {
        const float4* xm4 = reinterpret_cast<const float4*>(&s_xn[m][0]);
        float4 a0 = xm4[0], a1 = xm4[1], a2 = xm4[2], a3 = xm4[3];
        float dot = 0.0f;
        dot = fmaf(xnr[0],  a0.x, dot); dot = fmaf(xnr[1],  a0.y, dot);
        dot = fmaf(xnr[2],  a0.z, dot); dot = fmaf(xnr[3],  a0.w, dot);
        dot = fmaf(xnr[4],  a1.x, dot); dot = fmaf(xnr[5],  a1.y, dot);
        dot = fmaf(xnr[6],  a1.z, dot); dot = fmaf(xnr[7],  a1.w, dot);
        dot = fmaf(xnr[8],  a2.x, dot); dot = fmaf(xnr[9],  a2.y, dot);
        dot = fmaf(xnr[10], a2.z, dot); dot = fmaf(xnr[11], a2.w, dot);
        dot = fmaf(xnr[12], a3.x, dot); dot = fmaf(xnr[13], a3.y, dot);
        dot = fmaf(xnr[14], a3.z, dot); dot = fmaf(xnr[15], a3.w, dot);

        int di = pi - (m >> 4);
        int dj = pj - (m & 15);
        float sd = s_table[di * di + dj * dj];
        float comb = __fadd_rn(__fmul_rn(alpha, dot), __fmul_rn(oma, sd));

        if (comb > tv[KK - 1]) {
            float cv = comb; int ci = m;
            #pragma unroll
            for (int t = KK - 1; t >= 0; --t) {
                bool g = (cv > tv[t]);
                float ov = tv[t]; int oi = ti[t];
                if (g) {
                    if (t + 1 < KK) { tv[t + 1] = ov; ti[t + 1] = oi; }
                    tv[t] = cv; ti[t] = ci;
                }
            }
        }
    }

    float wk[KK];
    float wsum = 0.0f;
    #pragma unroll
    for (int k = 0; k < KK; ++k) {
        int m = ti[k];
        int di = pi - (m >> 4);
        int dj = pj - (m & 15);
        float sd = s_table[di * di + dj * dj];
        float sf = (tv[k] - __fmul_rn(oma, sd)) / alpha;
        float hsum = b2r;
        #pragma unroll
        for (int h = 0; h < 4; ++h) {
            float z  = fmaf(sf, W1r[2 * h], fmaf(sd, W1r[2 * h + 1], b1r[h]));
            float sg = 1.0f / (1.0f + expf(-z));
            hsum = fmaf(z * sg, W2r[h], hsum);
        }
        float wg = 1.0f / (1.0f + expf(-hsum));
        wk[k] = wg;
        wsum += wg;
    }
    wsum += 1e-12f;

    float outv[CF];
    #pragma unroll
    for (int o = 0; o < CF; ++o) outv[o] = 0.0f;
    #pragma unroll
    for (int k = 0; k < KK; ++k) {
        float wn = wk[k] / wsum;
        int m = ti[k];
        const float4* xf4 = reinterpret_cast<const float4*>(&s_xf[m][0]);
        float4 m0 = xf4[0], m1 = xf4[1], m2 = xf4[2], m3 = xf4[3];
        outv[0]  = fmaf(wn, m0.x, outv[0]);  outv[1]  = fmaf(wn, m0.y, outv[1]);
        outv[2]  = fmaf(wn, m0.z, outv[2]);  outv[3]  = fmaf(wn, m0.w, outv[3]);
        outv[4]  = fmaf(wn, m1.x, outv[4]);  outv[5]  = fmaf(wn, m1.y, outv[5]);
        outv[6]  = fmaf(wn, m1.z, outv[6]);  outv[7]  = fmaf(wn, m1.w, outv[7]);
        outv[8]  = fmaf(wn, m2.x, outv[8]);  outv[9]  = fmaf(wn, m2.y, outv[9]);
        outv[10] = fmaf(wn, m2.z, outv[10]); outv[11] = fmaf(wn, m2.w, outv[11]);
        outv[12] = fmaf(wn, m3.x, outv[12]); outv[13] = fmaf(wn, m3.y, outv[13]);
        outv[14] = fmaf(wn, m3.z, outv[14]); outv[15] = fmaf(wn, m3.w, outv[15]);
    }

    __syncthreads();
    for (int t = tid; t < CC * CF; t += NPIX) s_W[t] = Wp[t];
    if (tid < CC) s_bias[tid] = bp[tid];
    __syncthreads();

    float* yb = y + (size_t)bb * CC * HWQ + (size_t)gy * WWQ + gx;
    for (int o = 0; o < CC; ++o) {
        float acc = 0.0f;
        #pragma unroll
        for (int c = 0; c < CF; ++c)
            acc = fmaf(outv[c], s_W[o * CF + c], acc);
        yb[(size_t)o * HWQ] = acc + s_bias[o];
    }
}

extern "C" void kernel_launch(void* const* d_in, const int* in_sizes, int n_in,
                              void* d_out, int out_size, void* d_ws, size_t ws_size,
                              hipStream_t stream) {
    const float* x_in  = (const float*)d_in[0];
    const float* Wf    = (const float*)d_in[1];
    const float* bf    = (const float*)d_in[2];
    const float* Wp    = (const float*)d_in[3];
    const float* bp    = (const float*)d_in[4];
    const float* W1    = (const float*)d_in[5];
    const float* b1    = (const float*)d_in[6];
    const float* W2    = (const float*)d_in[7];
    const float* b2    = (const float*)d_in[8];
    const float* sigma = (const float*)d_in[9];
    const float* alpha = (const float*)d_in[10];
    float* y = (float*)d_out;

    const size_t need1 = (size_t)(NROWS * (CF + 1)) * sizeof(float);
    const size_t need2 = need1 + (size_t)(2 * KK * NROWS) * sizeof(float);
    if (ws_size >= need2) {
        float* xn_g  = (float*)d_ws;
        float* nrm_g = xn_g + (size_t)NROWS * CF;
        float* pval  = nrm_g + NROWS;
        int*   pidx  = (int*)(pval + (size_t)KK * NROWS);
        feat_k<<<3136, 64, 0, stream>>>(x_in, Wf, bf, xn_g, nrm_g);
        gnn_split<<<NTILE * 2, 256, 0, stream>>>(xn_g, nrm_g, Wp, bp, W1, b1,
                                                 W2, b2, sigma, alpha,
                                                 pval, pidx, y);
    } else if (ws_size >= need1) {
        float* xn_g  = (float*)d_ws;
        float* nrm_g = xn_g + (size_t)NROWS * CF;
        feat_k<<<3136, 64, 0, stream>>>(x_in, Wf, bf, xn_g, nrm_g);
        gnn_main_r5<<<NTILE * 2, MBLK, 0, stream>>>(xn_g, nrm_g, Wp, bp, W1, b1,
                                                    W2, b2, sigma, alpha, y);
    } else {
        gnn_fused<<<NTILE, NPIX, 0, stream>>>(x_in, Wf, bf, Wp, bp, W1, b1, W2,
                                              b2, sigma, alpha, y);
    }
}

// Round 7
// 129.357 us; speedup vs baseline: 1.3543x; 1.3543x over previous
//
#include <hip/hip_runtime.h>
#include <math.h>

// B=16, C=64, H=W=112, WS=7 -> 784 tiles of 16x16 pixels
#define CC    64
#define CF    16
#define NPIX  256
#define KK    9
#define HWQ   12544
#define WWQ   112
#define NTILE 784
#define NROWS (NTILE * NPIX)   // 200704

// ============================================================
// Kernel 1: per-pixel features f = Wf@x + bf, normalize.
// ============================================================
__global__ __launch_bounds__(64, 4) void feat_k(
    const float* __restrict__ x_in, const float* __restrict__ Wf,
    const float* __restrict__ bf,
    float* __restrict__ xn_g, float* __restrict__ nrm_g)
{
    __shared__ float s_Wt[CC * CF];   // transposed [c][o]
    __shared__ float s_bf[CF];
    const int tid = threadIdx.x;
    for (int idx = tid; idx < CC * CF; idx += 64) {
        int c = idx >> 4, o = idx & 15;
        s_Wt[idx] = Wf[o * CC + c];
    }
    if (tid < CF) s_bf[tid] = bf[tid];
    __syncthreads();

    const int p    = blockIdx.x * 64 + tid;
    const int tile = p >> 8, pix = p & 255;
    const int bb = tile / 49, ssb = tile % 49;
    const int s1 = ssb / 7, s2 = ssb % 7;
    const int gy = s1 * 16 + (pix >> 4), gx = s2 * 16 + (pix & 15);
    const float* xb = x_in + (size_t)bb * CC * HWQ + (size_t)gy * WWQ + gx;

    float fv[CF];
    #pragma unroll
    for (int o = 0; o < CF; ++o) fv[o] = 0.0f;
    #pragma unroll 8
    for (int c = 0; c < CC; ++c) {
        float xv = xb[(size_t)c * HWQ];
        const float4* w4 = reinterpret_cast<const float4*>(&s_Wt[c << 4]);
        float4 w0 = w4[0], w1 = w4[1], w2 = w4[2], w3 = w4[3];
        fv[0]  = fmaf(xv, w0.x, fv[0]);  fv[1]  = fmaf(xv, w0.y, fv[1]);
        fv[2]  = fmaf(xv, w0.z, fv[2]);  fv[3]  = fmaf(xv, w0.w, fv[3]);
        fv[4]  = fmaf(xv, w1.x, fv[4]);  fv[5]  = fmaf(xv, w1.y, fv[5]);
        fv[6]  = fmaf(xv, w1.z, fv[6]);  fv[7]  = fmaf(xv, w1.w, fv[7]);
        fv[8]  = fmaf(xv, w2.x, fv[8]);  fv[9]  = fmaf(xv, w2.y, fv[9]);
        fv[10] = fmaf(xv, w2.z, fv[10]); fv[11] = fmaf(xv, w2.w, fv[11]);
        fv[12] = fmaf(xv, w3.x, fv[12]); fv[13] = fmaf(xv, w3.y, fv[13]);
        fv[14] = fmaf(xv, w3.z, fv[14]); fv[15] = fmaf(xv, w3.w, fv[15]);
    }
    #pragma unroll
    for (int o = 0; o < CF; ++o) fv[o] += s_bf[o];

    float ss2 = 0.0f;
    #pragma unroll
    for (int o = 0; o < CF; ++o) ss2 = fmaf(fv[o], fv[o], ss2);
    float nrm = fmaxf(sqrtf(ss2), 1e-8f);

    float xn[CF];
    #pragma unroll
    for (int o = 0; o < CF; ++o) xn[o] = fv[o] / nrm;

    float4* dst = reinterpret_cast<float4*>(xn_g + (size_t)p * CF);
    dst[0] = make_float4(xn[0],  xn[1],  xn[2],  xn[3]);
    dst[1] = make_float4(xn[4],  xn[5],  xn[6],  xn[7]);
    dst[2] = make_float4(xn[8],  xn[9],  xn[10], xn[11]);
    dst[3] = make_float4(xn[12], xn[13], xn[14], xn[15]);
    nrm_g[p] = nrm;
}

// ---------------- shared scan machinery ----------------
#define DOT16(dot, a0, a1, a2, a3)                                   \
    dot = fmaf(xnr[0],  (a0).x, dot); dot = fmaf(xnr[1],  (a0).y, dot); \
    dot = fmaf(xnr[2],  (a0).z, dot); dot = fmaf(xnr[3],  (a0).w, dot); \
    dot = fmaf(xnr[4],  (a1).x, dot); dot = fmaf(xnr[5],  (a1).y, dot); \
    dot = fmaf(xnr[6],  (a1).z, dot); dot = fmaf(xnr[7],  (a1).w, dot); \
    dot = fmaf(xnr[8],  (a2).x, dot); dot = fmaf(xnr[9],  (a2).y, dot); \
    dot = fmaf(xnr[10], (a2).z, dot); dot = fmaf(xnr[11], (a2).w, dot); \
    dot = fmaf(xnr[12], (a3).x, dot); dot = fmaf(xnr[13], (a3).y, dot); \
    dot = fmaf(xnr[14], (a3).z, dot); dot = fmaf(xnr[15], (a3).w, dot);

// guard-free sorted top-9 insert; strict '>' keeps lower index on ties,
// matching lax.top_k. Values via max/med3, indices via monotone cndmasks.
#define TOP9_INSERT(cv, ci) {                                        \
    const bool g0 = (cv) > tv0; const bool g1 = (cv) > tv1;          \
    const bool g2 = (cv) > tv2; const bool g3 = (cv) > tv3;          \
    const bool g4 = (cv) > tv4; const bool g5 = (cv) > tv5;          \
    const bool g6 = (cv) > tv6; const bool g7 = (cv) > tv7;          \
    const bool g8 = (cv) > tv8;                                      \
    const float nv0 = g0 ? (cv) : tv0;                               \
    const float nv1 = __builtin_amdgcn_fmed3f((cv), tv0, tv1);       \
    const float nv2 = __builtin_amdgcn_fmed3f((cv), tv1, tv2);       \
    const float nv3 = __builtin_amdgcn_fmed3f((cv), tv2, tv3);       \
    const float nv4 = __builtin_amdgcn_fmed3f((cv), tv3, tv4);       \
    const float nv5 = __builtin_amdgcn_fmed3f((cv), tv4, tv5);       \
    const float nv6 = __builtin_amdgcn_fmed3f((cv), tv5, tv6);       \
    const float nv7 = __builtin_amdgcn_fmed3f((cv), tv6, tv7);       \
    const float nv8 = __builtin_amdgcn_fmed3f((cv), tv7, tv8);       \
    const int nt0 = g0 ? (ci) : ti0;                                 \
    const int nt1 = g0 ? ti0 : (g1 ? (ci) : ti1);                    \
    const int nt2 = g1 ? ti1 : (g2 ? (ci) : ti2);                    \
    const int nt3 = g2 ? ti2 : (g3 ? (ci) : ti3);                    \
    const int nt4 = g3 ? ti3 : (g4 ? (ci) : ti4);                    \
    const int nt5 = g4 ? ti4 : (g5 ? (ci) : ti5);                    \
    const int nt6 = g5 ? ti5 : (g6 ? (ci) : ti6);                    \
    const int nt7 = g6 ? ti6 : (g7 ? (ci) : ti7);                    \
    const int nt8 = g7 ? ti7 : (g8 ? (ci) : ti8);                    \
    tv0 = nv0; tv1 = nv1; tv2 = nv2; tv3 = nv3; tv4 = nv4;           \
    tv5 = nv5; tv6 = nv6; tv7 = nv7; tv8 = nv8;                      \
    ti0 = nt0; ti1 = nt1; ti2 = nt2; ti3 = nt3; ti4 = nt4;           \
    ti5 = nt5; ti6 = nt6; ti7 = nt7; ti8 = nt8; }

#define SIM_ITER(MJ) {                                               \
    const int m = mbase + (MJ);                                      \
    const float4* xm4 = reinterpret_cast<const float4*>(&s_xn[m][0]);\
    const float4 a0 = xm4[0], a1 = xm4[1], a2 = xm4[2], a3 = xm4[3]; \
    float dot = 0.0f;                                                \
    DOT16(dot, a0, a1, a2, a3);                                      \
    const int dj = pj - (MJ);                                        \
    const float sdA = s_tabA[d2i + dj * dj];                         \
    const float comb = __fadd_rn(__fmul_rn(alpha, dot), sdA);        \
    TOP9_INSERT(comb, m); }

#define SIM_ROW16()                                                  \
        SIM_ITER(0)  SIM_ITER(1)  SIM_ITER(2)  SIM_ITER(3)           \
        SIM_ITER(4)  SIM_ITER(5)  SIM_ITER(6)  SIM_ITER(7)           \
        SIM_ITER(8)  SIM_ITER(9)  SIM_ITER(10) SIM_ITER(11)          \
        SIM_ITER(12) SIM_ITER(13) SIM_ITER(14) SIM_ITER(15)

// ============================================================
// Kernel 2: candidate-split scan, LDS partial merge.
// Block = 256 threads: 128 rows x 2 candidate halves (4 waves share
// one staged tile). Hi-half waves write sorted partial top-9 to LDS;
// after one barrier, lo-half waves merge via the identical
// TOP9_INSERT (exact lax.top_k tie semantics) and run the epilogue.
// ============================================================
__global__ __launch_bounds__(256, 4) void gnn_split(
    const float* __restrict__ xn_g, const float* __restrict__ nrm_g,
    const float* __restrict__ Wp,   const float* __restrict__ bp,
    const float* __restrict__ W1,   const float* __restrict__ b1,
    const float* __restrict__ W2,   const float* __restrict__ b2,
    const float* __restrict__ sigma_p, const float* __restrict__ alpha_p,
    float* __restrict__ y)
{
    __shared__ float s_xn[NPIX][CF];   // 16 KB tile features
    __shared__ float s_nrm[NPIX];      // 1 KB
    __shared__ float s_tab[451];       // raw exp(-d^2/(2 sigma^2))
    __shared__ float s_tabA[451];      // (1-alpha) * table
    __shared__ float s_pv[KK][128];    // 4.5 KB hi-half partial values
    __shared__ int   s_pi[KK][128];    // 4.5 KB hi-half partial indices

    const int bid  = blockIdx.x;
    const int tile = bid >> 1;
    const int hlf  = bid & 1;          // row half of the tile
    const int bb = tile / 49, ssb = tile % 49;
    const int s1 = ssb / 7, s2 = ssb % 7;
    const int tid = threadIdx.x;
    const int rl  = tid & 127;         // row within half
    const int ch  = tid >> 7;          // candidate half (0 = lo, 1 = hi)

    const float alpha = alpha_p[0];
    const float oma   = 1.0f - alpha;
    const float sig   = sigma_p[0];
    const float denom = 2.0f * sig * sig;

    for (int t = tid; t < 451; t += 256) {
        float dd = sqrtf((float)t);
        float v  = expf((-(dd * dd)) / denom);
        s_tab[t]  = v;
        s_tabA[t] = __fmul_rn(oma, v);
    }
    const float* xt = xn_g + (size_t)tile * NPIX * CF;
    {
        const float4* src = reinterpret_cast<const float4*>(xt);
        float4*       dst = reinterpret_cast<float4*>(&s_xn[0][0]);
        #pragma unroll
        for (int i = 0; i < 4; ++i) dst[tid + i * 256] = src[tid + i * 256];
        s_nrm[tid] = nrm_g[(size_t)tile * NPIX + tid];
    }
    float W1r[8], b1r[4], W2r[4];
    #pragma unroll
    for (int h = 0; h < 8; ++h) W1r[h] = W1[h];
    #pragma unroll
    for (int h = 0; h < 4; ++h) { b1r[h] = b1[h]; W2r[h] = W2[h]; }
    const float b2r = b2[0];
    __syncthreads();

    const int r  = hlf * 128 + rl;     // this thread's row 0..255
    const int pi = r >> 4, pj = r & 15;

    float xnr[CF];
    {
        const float4* xr4 = reinterpret_cast<const float4*>(&s_xn[r][0]);
        float4 r0 = xr4[0], r1 = xr4[1], r2 = xr4[2], r3 = xr4[3];
        xnr[0]=r0.x;  xnr[1]=r0.y;  xnr[2]=r0.z;  xnr[3]=r0.w;
        xnr[4]=r1.x;  xnr[5]=r1.y;  xnr[6]=r1.z;  xnr[7]=r1.w;
        xnr[8]=r2.x;  xnr[9]=r2.y;  xnr[10]=r2.z; xnr[11]=r2.w;
        xnr[12]=r3.x; xnr[13]=r3.y; xnr[14]=r3.z; xnr[15]=r3.w;
    }

    float tv0,tv1,tv2,tv3,tv4,tv5,tv6,tv7,tv8;
    int   ti0,ti1,ti2,ti3,ti4,ti5,ti6,ti7,ti8;
    tv0=tv1=tv2=tv3=tv4=tv5=tv6=tv7=tv8 = -INFINITY;
    ti0=ti1=ti2=ti3=ti4=ti5=ti6=ti7=ti8 = 0;

    // scan this thread's candidate half: mi in [ch*8, ch*8+8)
    const int mi0 = ch << 3;
    #pragma unroll 1
    for (int q = 0; q < 8; ++q) {
        const int mi  = mi0 + q;
        const int di  = pi - mi;
        const int d2i = di * di;
        const int mbase = mi << 4;
        SIM_ROW16()
    }

    // hi-half waves publish their sorted partials to LDS
    if (ch == 1) {
        s_pv[0][rl] = tv0; s_pi[0][rl] = ti0;
        s_pv[1][rl] = tv1; s_pi[1][rl] = ti1;
        s_pv[2][rl] = tv2; s_pi[2][rl] = ti2;
        s_pv[3][rl] = tv3; s_pi[3][rl] = ti3;
        s_pv[4][rl] = tv4; s_pi[4][rl] = ti4;
        s_pv[5][rl] = tv5; s_pi[5][rl] = ti5;
        s_pv[6][rl] = tv6; s_pi[6][rl] = ti6;
        s_pv[7][rl] = tv7; s_pi[7][rl] = ti7;
        s_pv[8][rl] = tv8; s_pi[8][rl] = ti8;
    }
    __syncthreads();
    if (ch == 1) return;

    // lo-half waves merge hi partials: sorted-desc b0..b8 inserted in order
    // through the identical strict-'>' insert => exact 256-wide semantics
    // (all lo indices < hi indices, ties keep lo; hi internal order kept).
    #pragma unroll
    for (int k = 0; k < KK; ++k) {
        const float bv = s_pv[k][rl];
        const int   bi = s_pi[k][rl];
        TOP9_INSERT(bv, bi);
    }

    const float tv[KK] = {tv0,tv1,tv2,tv3,tv4,tv5,tv6,tv7,tv8};
    const int   ti[KK] = {ti0,ti1,ti2,ti3,ti4,ti5,ti6,ti7,ti8};

    // ---- edge MLP weights ----
    float wk[KK];
    float wsum = 0.0f;
    #pragma unroll
    for (int k = 0; k < KK; ++k) {
        int m = ti[k];
        int di = pi - (m >> 4);
        int dj = pj - (m & 15);
        float sd = s_tab[di * di + dj * dj];
        float sf = (tv[k] - __fmul_rn(oma, sd)) / alpha;
        float hsum = b2r;
        #pragma unroll
        for (int h = 0; h < 4; ++h) {
            float z  = fmaf(sf, W1r[2 * h], fmaf(sd, W1r[2 * h + 1], b1r[h]));
            float sg = 1.0f / (1.0f + expf(-z));
            hsum = fmaf(z * sg, W2r[h], hsum);
        }
        float wg = 1.0f / (1.0f + expf(-hsum));
        wk[k] = wg;
        wsum += wg;
    }
    wsum += 1e-12f;

    // ---- aggregate messages (msg = xn * nrm) ----
    float outv[CF];
    #pragma unroll
    for (int o = 0; o < CF; ++o) outv[o] = 0.0f;
    #pragma unroll
    for (int k = 0; k < KK; ++k) {
        const int m = ti[k];
        const float wnm = (wk[k] / wsum) * s_nrm[m];
        const float4* xf4 = reinterpret_cast<const float4*>(&s_xn[m][0]);
        float4 m0 = xf4[0], m1 = xf4[1], m2 = xf4[2], m3 = xf4[3];
        outv[0]  = fmaf(wnm, m0.x, outv[0]);  outv[1]  = fmaf(wnm, m0.y, outv[1]);
        outv[2]  = fmaf(wnm, m0.z, outv[2]);  outv[3]  = fmaf(wnm, m0.w, outv[3]);
        outv[4]  = fmaf(wnm, m1.x, outv[4]);  outv[5]  = fmaf(wnm, m1.y, outv[5]);
        outv[6]  = fmaf(wnm, m1.z, outv[6]);  outv[7]  = fmaf(wnm, m1.w, outv[7]);
        outv[8]  = fmaf(wnm, m2.x, outv[8]);  outv[9]  = fmaf(wnm, m2.y, outv[9]);
        outv[10] = fmaf(wnm, m2.z, outv[10]); outv[11] = fmaf(wnm, m2.w, outv[11]);
        outv[12] = fmaf(wnm, m3.x, outv[12]); outv[13] = fmaf(wnm, m3.y, outv[13]);
        outv[14] = fmaf(wnm, m3.z, outv[14]); outv[15] = fmaf(wnm, m3.w, outv[15]);
    }

    // ---- project 16 -> 64, store (Wp/bp uniform from L1/L2) ----
    const int gy = s1 * 16 + pi, gx = s2 * 16 + pj;
    float* yb = y + (size_t)bb * CC * HWQ + (size_t)gy * WWQ + gx;
    #pragma unroll 4
    for (int o = 0; o < CC; ++o) {
        const float4* w4 = reinterpret_cast<const float4*>(&Wp[o * CF]);
        float4 w0 = w4[0], w1 = w4[1], w2 = w4[2], w3 = w4[3];
        float acc = 0.0f;
        acc = fmaf(outv[0],  w0.x, acc); acc = fmaf(outv[1],  w0.y, acc);
        acc = fmaf(outv[2],  w0.z, acc); acc = fmaf(outv[3],  w0.w, acc);
        acc = fmaf(outv[4],  w1.x, acc); acc = fmaf(outv[5],  w1.y, acc);
        acc = fmaf(outv[6],  w1.z, acc); acc = fmaf(outv[7],  w1.w, acc);
        acc = fmaf(outv[8],  w2.x, acc); acc = fmaf(outv[9],  w2.y, acc);
        acc = fmaf(outv[10], w2.z, acc); acc = fmaf(outv[11], w2.w, acc);
        acc = fmaf(outv[12], w3.x, acc); acc = fmaf(outv[13], w3.y, acc);
        acc = fmaf(outv[14], w3.z, acc); acc = fmaf(outv[15], w3.w, acc);
        yb[(size_t)o * HWQ] = acc + bp[o];
    }
}

// ============================================================
// Fallback: round-1 fused kernel (no workspace needed).
// ============================================================
__global__ __launch_bounds__(256) void gnn_fused(
    const float* __restrict__ x_in, const float* __restrict__ Wf,
    const float* __restrict__ bf,   const float* __restrict__ Wp,
    const float* __restrict__ bp,   const float* __restrict__ W1,
    const float* __restrict__ b1,   const float* __restrict__ W2,
    const float* __restrict__ b2,   const float* __restrict__ sigma_p,
    const float* __restrict__ alpha_p, float* __restrict__ y)
{
    __shared__ float s_xf[NPIX][CF];
    __shared__ float s_xn[NPIX][CF];
    __shared__ float s_W[CC * CF];
    __shared__ float s_table[451];
    __shared__ float s_bias[CC];

    const int bpi = blockIdx.x;
    const int bb  = bpi / 49;
    const int ssb = bpi % 49;
    const int s1  = ssb / 7, s2 = ssb % 7;
    const int tid = threadIdx.x;
    const int pi  = tid >> 4, pj = tid & 15;
    const int gy  = s1 * 16 + pi, gx = s2 * 16 + pj;

    const float alpha = alpha_p[0];
    const float oma   = 1.0f - alpha;
    const float sig   = sigma_p[0];
    const float denom = 2.0f * sig * sig;

    for (int t = tid; t < CF * CC; t += NPIX) s_W[t] = Wf[t];
    if (tid < CF) s_bias[tid] = bf[tid];
    for (int t = tid; t < 451; t += NPIX) {
        float dd = sqrtf((float)t);
        s_table[t] = expf((-(dd * dd)) / denom);
    }
    float W1r[8], b1r[4], W2r[4];
    #pragma unroll
    for (int h = 0; h < 8; ++h) W1r[h] = W1[h];
    #pragma unroll
    for (int h = 0; h < 4; ++h) { b1r[h] = b1[h]; W2r[h] = W2[h]; }
    const float b2r = b2[0];
    __syncthreads();

    const float* xb = x_in + (size_t)bb * CC * HWQ + (size_t)gy * WWQ + gx;
    float fv[CF];
    #pragma unroll
    for (int o = 0; o < CF; ++o) fv[o] = 0.0f;
    for (int c = 0; c < CC; ++c) {
        float xv = xb[(size_t)c * HWQ];
        #pragma unroll
        for (int o = 0; o < CF; ++o)
            fv[o] = fmaf(xv, s_W[o * CC + c], fv[o]);
    }
    #pragma unroll
    for (int o = 0; o < CF; ++o) fv[o] += s_bias[o];

    float ss2 = 0.0f;
    #pragma unroll
    for (int o = 0; o < CF; ++o) ss2 = fmaf(fv[o], fv[o], ss2);
    float nrm = fmaxf(sqrtf(ss2), 1e-8f);

    float xnr[CF];
    #pragma unroll
    for (int o = 0; o < CF; ++o) {
        xnr[o] = fv[o] / nrm;
        s_xf[tid][o] = fv[o];
        s_xn[tid][o] = xnr[o];
    }
    __syncthreads();

    float tv[KK]; int ti[KK];
    #pragma unroll
    for (int k = 0; k < KK; ++k) { tv[k] = -INFINITY; ti[k] = 0; }

    for (int m = 0; m < NPIX; ++m) {
        const float4* xm4 = reinterpret_cast<const float4*>(&s_xn[m][0]);
        float4 a0 = xm4[0], a1 = xm4[1], a2 = xm4[2], a3 = xm4[3];
        float dot = 0.0f;
        dot = fmaf(xnr[0],  a0.x, dot); dot = fmaf(xnr[1],  a0.y, dot);
        dot = fmaf(xnr[2],  a0.z, dot); dot = fmaf(xnr[3],  a0.w, dot);
        dot = fmaf(xnr[4],  a1.x, dot); dot = fmaf(xnr[5],  a1.y, dot);
        dot = fmaf(xnr[6],  a1.z, dot); dot = fmaf(xnr[7],  a1.w, dot);
        dot = fmaf(xnr[8],  a2.x, dot); dot = fmaf(xnr[9],  a2.y, dot);
        dot = fmaf(xnr[10], a2.z, dot); dot = fmaf(xnr[11], a2.w, dot);
        dot = fmaf(xnr[12], a3.x, dot); dot = fmaf(xnr[13], a3.y, dot);
        dot = fmaf(xnr[14], a3.z, dot); dot = fmaf(xnr[15], a3.w, dot);

        int di = pi - (m >> 4);
        int dj = pj - (m & 15);
        float sd = s_table[di * di + dj * dj];
        float comb = __fadd_rn(__fmul_rn(alpha, dot), __fmul_rn(oma, sd));

        if (comb > tv[KK - 1]) {
            float cv = comb; int ci = m;
            #pragma unroll
            for (int t = KK - 1; t >= 0; --t) {
                bool g = (cv > tv[t]);
                float ov = tv[t]; int oi = ti[t];
                if (g) {
                    if (t + 1 < KK) { tv[t + 1] = ov; ti[t + 1] = oi; }
                    tv[t] = cv; ti[t] = ci;
                }
            }
        }
    }

    float wk[KK];
    float wsum = 0.0f;
    #pragma unroll
    for (int k = 0; k < KK; ++k) {
        int m = ti[k];
        int di = pi - (m >> 4);
        int dj = pj - (m & 15);
        float sd = s_table[di * di + dj * dj];
        float sf = (tv[k] - __fmul_rn(oma, sd)) / alpha;
        float hsum = b2r;
        #pragma unroll
        for (int h = 0; h < 4; ++h) {
            float z  = fmaf(sf, W1r[2 * h], fmaf(sd, W1r[2 * h + 1], b1r[h]));
            float sg = 1.0f / (1.0f + expf(-z));
            hsum = fmaf(z * sg, W2r[h], hsum);
        }
        float wg = 1.0f / (1.0f + expf(-hsum));
        wk[k] = wg;
        wsum += wg;
    }
    wsum += 1e-12f;

    float outv[CF];
    #pragma unroll
    for (int o = 0; o < CF; ++o) outv[o] = 0.0f;
    #pragma unroll
    for (int k = 0; k < KK; ++k) {
        float wn = wk[k] / wsum;
        int m = ti[k];
        const float4* xf4 = reinterpret_cast<const float4*>(&s_xf[m][0]);
        float4 m0 = xf4[0], m1 = xf4[1], m2 = xf4[2], m3 = xf4[3];
        outv[0]  = fmaf(wn, m0.x, outv[0]);  outv[1]  = fmaf(wn, m0.y, outv[1]);
        outv[2]  = fmaf(wn, m0.z, outv[2]);  outv[3]  = fmaf(wn, m0.w, outv[3]);
        outv[4]  = fmaf(wn, m1.x, outv[4]);  outv[5]  = fmaf(wn, m1.y, outv[5]);
        outv[6]  = fmaf(wn, m1.z, outv[6]);  outv[7]  = fmaf(wn, m1.w, outv[7]);
        outv[8]  = fmaf(wn, m2.x, outv[8]);  outv[9]  = fmaf(wn, m2.y, outv[9]);
        outv[10] = fmaf(wn, m2.z, outv[10]); outv[11] = fmaf(wn, m2.w, outv[11]);
        outv[12] = fmaf(wn, m3.x, outv[12]); outv[13] = fmaf(wn, m3.y, outv[13]);
        outv[14] = fmaf(wn, m3.z, outv[14]); outv[15] = fmaf(wn, m3.w, outv[15]);
    }

    __syncthreads();
    for (int t = tid; t < CC * CF; t += NPIX) s_W[t] = Wp[t];
    if (tid < CC) s_bias[tid] = bp[tid];
    __syncthreads();

    float* yb = y + (size_t)bb * CC * HWQ + (size_t)gy * WWQ + gx;
    for (int o = 0; o < CC; ++o) {
        float acc = 0.0f;
        #pragma unroll
        for (int c = 0; c < CF; ++c)
            acc = fmaf(outv[c], s_W[o * CF + c], acc);
        yb[(size_t)o * HWQ] = acc + s_bias[o];
    }
}

extern "C" void kernel_launch(void* const* d_in, const int* in_sizes, int n_in,
                              void* d_out, int out_size, void* d_ws, size_t ws_size,
                              hipStream_t stream) {
    const float* x_in  = (const float*)d_in[0];
    const float* Wf    = (const float*)d_in[1];
    const float* bf    = (const float*)d_in[2];
    const float* Wp    = (const float*)d_in[3];
    const float* bp    = (const float*)d_in[4];
    const float* W1    = (const float*)d_in[5];
    const float* b1    = (const float*)d_in[6];
    const float* W2    = (const float*)d_in[7];
    const float* b2    = (const float*)d_in[8];
    const float* sigma = (const float*)d_in[9];
    const float* alpha = (const float*)d_in[10];
    float* y = (float*)d_out;

    const size_t need = (size_t)(NROWS * (CF + 1)) * sizeof(float);
    if (ws_size >= need) {
        float* xn_g  = (float*)d_ws;
        float* nrm_g = xn_g + (size_t)NROWS * CF;
        feat_k<<<3136, 64, 0, stream>>>(x_in, Wf, bf, xn_g, nrm_g);
        gnn_split<<<NTILE * 2, 256, 0, stream>>>(xn_g, nrm_g, Wp, bp, W1, b1,
                                                 W2, b2, sigma, alpha, y);
    } else {
        gnn_fused<<<NTILE, NPIX, 0, stream>>>(x_in, Wf, bf, Wp, bp, W1, b1, W2,
                                              b2, sigma, alpha, y);
    }
}